// Round 11
// baseline (212.712 us; speedup 1.0000x reference)
//
#include <hip/hip_runtime.h>
#include <math.h>

// CrossAttention B=2,S=2048,E=1024,H=16,Dh=64,NC=768 — fp32 in/out.
// Ledger: R11 216.4 | R18 qkv 8-wave 215.1 | R19 (attn merge + qkv 3-deep
// counted-vmcnt) 208.2. Fixed ~81us harness fill floor inside timed window
// (2x40.7us, 268MB re-poison) — reconciles all totals. Controllable budget
// ~127us: attn 46.4, qkv ~36, gemm_out ~30(est, never measured), prep ~15.
// R20: gemm_out retile 128x128 -> 128x64 (grid 256->512 blocks = 2/CU,
//   16 waves/CU vs 8): the only kernel at 1 block/CU (25% occupancy hard
//   cap) and the only one never touched. 8 waves as wm=w&3 (32-row strips)
//   x wn=w>>2 (two 32-col strips), acc[1]/wave. A-combine path unchanged
//   (128x32, all-thread ds_write); B-tile 4KB staged by waves 0-3 (sigma
//   closed under t<256); LDS 24KB. qkv/attn/prep unchanged from R19.

namespace {

typedef short bfr __attribute__((ext_vector_type(8)));   // 8 bf16 = 4 VGPR
typedef short s4v __attribute__((ext_vector_type(4)));
typedef unsigned u4v __attribute__((ext_vector_type(4)));
typedef float accf __attribute__((ext_vector_type(16)));

#define MFMA32(a, b, c) __builtin_amdgcn_mfma_f32_32x32x16_bf16(a, b, c, 0, 0, 0)

__device__ inline short f2bf(float f) {  // RNE
    unsigned u = __float_as_uint(f);
    u += 0x7fffu + ((u >> 16) & 1u);
    return (short)(u >> 16);
}
__device__ inline float bf2f(short s) {
    return __uint_as_float(((unsigned)(unsigned short)s) << 16);
}
__device__ inline float fexp2(float x) { return __builtin_amdgcn_exp2f(x); }
__device__ inline accf zero16() {
    accf z;
#pragma unroll
    for (int i = 0; i < 16; ++i) z[i] = 0.f;
    return z;
}
__device__ inline void dma16(const void* g, void* l) {
    __builtin_amdgcn_global_load_lds(
        (const __attribute__((address_space(1))) void*)g,
        (__attribute__((address_space(3))) void*)l, 16, 0, 0);
}

// ---------- prep: tobf (x,ctx) + all 4 weight transposes, one dispatch ----
__global__ __launch_bounds__(256) void prep(
    const float* __restrict__ x, const float* __restrict__ ctx,
    short* __restrict__ xb, short* __restrict__ cb,
    const float* __restrict__ Wq, const float* __restrict__ Wk,
    const float* __restrict__ Wv, const float* __restrict__ Wo,
    short* __restrict__ Wqt, short* __restrict__ Wkt,
    short* __restrict__ Wvt, short* __restrict__ Wot) {
    __shared__ short t[64][68];
    const int bx = blockIdx.x;
    if (bx < 7168) {  // elementwise fp32->bf16
        int i = bx * 256 + threadIdx.x;
        if (i < 1048576) {
            float4 v = ((const float4*)x)[i];
            s4v p = {f2bf(v.x), f2bf(v.y), f2bf(v.z), f2bf(v.w)};
            ((s4v*)xb)[i] = p;
        } else {
            int j = i - 1048576;
            float4 v = ((const float4*)ctx)[j];
            s4v p = {f2bf(v.x), f2bf(v.y), f2bf(v.z), f2bf(v.w)};
            ((s4v*)cb)[j] = p;
        }
        return;
    }
    const int idx = bx - 7168;  // 0..1023
    const int z = idx >> 8, gy = (idx >> 4) & 15, gx = idx & 15;
    const float* W;
    short* Wt;
    int K;
    switch (z) {
        case 0: W = Wq; Wt = Wqt; K = 1024; break;
        case 1: W = Wk; Wt = Wkt; K = 768; break;
        case 2: W = Wv; Wt = Wvt; K = 768; break;
        default: W = Wo; Wt = Wot; K = 1024; break;
    }
    const int k0 = gy * 64;
    if (k0 >= K) return;
    const int tid = threadIdx.x;
    const int n0 = gx * 64;
    const int kr = tid >> 4, nc = (tid & 15) * 4;
#pragma unroll
    for (int rep = 0; rep < 4; ++rep) {
        int k = kr + rep * 16;
        float4 v = *(const float4*)&W[(size_t)(k0 + k) * 1024 + n0 + nc];
        t[nc + 0][k] = f2bf(v.x);
        t[nc + 1][k] = f2bf(v.y);
        t[nc + 2][k] = f2bf(v.z);
        t[nc + 3][k] = f2bf(v.w);
    }
    __syncthreads();
    const int nr = tid >> 4, kc = (tid & 15) * 4;
#pragma unroll
    for (int rep = 0; rep < 4; ++rep) {
        int n = nr + rep * 16;
        s4v p = {t[n][kc], t[n][kc + 1], t[n][kc + 2], t[n][kc + 3]};
        *(s4v*)&Wt[(size_t)(n0 + n) * K + k0 + kc] = p;
    }
}

// ---------- fused Q/K/V projection GEMM, 512 thr / 8 waves ----------------
// R19: 3-deep counted-vmcnt pipeline. XCD-swizzled 1D grid (768):
// z = bid>>8; local = bid&255; m = local&31, n = local>>5.
__global__ __launch_bounds__(512, 6) void gemm_qkv(
    const short* __restrict__ xb, const short* __restrict__ cb,
    const short* __restrict__ Wqt, const short* __restrict__ Wkt,
    const short* __restrict__ Wvt, const float* __restrict__ bq,
    const float* __restrict__ bk, const float* __restrict__ bv,
    short* __restrict__ Qf, short* __restrict__ Kf, short* __restrict__ Vt,
    float qscale) {
    const int bid = blockIdx.x;
    const int z = bid >> 8;
    const int local = bid & 255;
    const short* A  = (z == 0) ? xb : cb;
    const short* Bt = (z == 0) ? Wqt : ((z == 1) ? Wkt : Wvt);
    const float* bias = (z == 0) ? bq : ((z == 1) ? bk : bv);
    const int K = (z == 0) ? 1024 : 768;
    const int NIT = K / 32;
    const float scale = (z == 0) ? qscale : 1.f;
    short* out = (z == 0) ? Qf : ((z == 1) ? Kf : Vt);

    __shared__ short As[12288];  // 3 x 4096 (triple buffer)
    __shared__ short Bs[12288];
    const int t = threadIdx.x, lane = t & 63, w = t >> 6;  // w 0..7
    const int lm = lane & 31, h2 = lane >> 5;
    const int wm = w & 1, wn = w >> 1;  // wn 0..3
    const int m0 = (local & 31) * 128, n0 = (local >> 5) * 128;

    // staging: slot t holds global chunk sigma(t) = t ^ ((t>>3)&7)
    const int st = t ^ ((t >> 3) & 7);
    const int srow = st >> 2, scol = (st & 3) * 8;
    const short* ga = A + (size_t)(m0 + srow) * K + scol;
    const short* gb = Bt + (size_t)(n0 + srow) * K + scol;

    // read: slot = chunk ^ xorv, chunk = row*4 + colchunk
    const int xorv = (lm >> 1) & 7;
    const int rA0 = wm * 64 + lm, rB0 = wn * 32 + lm;

    accf acc[2] = {zero16(), zero16()};

    // prologue: batches 0,1 into bufs 0,1 (4 loads/thread outstanding)
    dma16(ga, &As[w * 512]);
    dma16(gb, &Bs[w * 512]);
    __builtin_amdgcn_sched_barrier(0);
    dma16(ga + 32, &As[4096 + w * 512]);
    dma16(gb + 32, &Bs[4096 + w * 512]);
    __builtin_amdgcn_sched_barrier(0);

    int buf = 0;  // buffer holding batch it
#pragma unroll 1
    for (int it = 0; it < NIT; ++it) {
        // batch(it) issued 2 iters ago; newest 2 batches stay in flight.
        __builtin_amdgcn_sched_barrier(0);
        asm volatile("s_waitcnt vmcnt(2)" ::: "memory");
        __builtin_amdgcn_s_barrier();
        __builtin_amdgcn_sched_barrier(0);
        {
            const int nx = (it + 2 >= NIT) ? (it + 2 - NIT) : (it + 2);
            const int nb = (buf + 2 >= 3) ? (buf - 1) : (buf + 2);
            dma16(ga + nx * 32, &As[nb * 4096 + w * 512]);
            dma16(gb + nx * 32, &Bs[nb * 4096 + w * 512]);
        }
        const short* bA = &As[buf * 4096];
        const short* bB = &Bs[buf * 4096];
#pragma unroll
        for (int kk8 = 0; kk8 < 4; kk8 += 2) {
            bfr a0 = *(const bfr*)&bA[((rA0 * 4 + h2 + kk8) ^ xorv) * 8];
            bfr a1 = *(const bfr*)&bA[(((rA0 + 32) * 4 + h2 + kk8) ^ xorv) * 8];
            bfr b0 = *(const bfr*)&bB[((rB0 * 4 + h2 + kk8) ^ xorv) * 8];
            acc[0] = MFMA32(a0, b0, acc[0]);
            acc[1] = MFMA32(a1, b0, acc[1]);
        }
        buf = (buf + 1 == 3) ? 0 : buf + 1;
    }
    // drain wrapped-tail DMAs before epilogue / endpgm (LDS reallocation).
    asm volatile("s_waitcnt vmcnt(0)" ::: "memory");
    __builtin_amdgcn_sched_barrier(0);

    const int n = n0 + wn * 32 + lm;
    const float bn = bias[n];
    const int hh = n >> 6, dd = n & 63;
#pragma unroll
    for (int mt = 0; mt < 2; ++mt) {
        const int mbase = m0 + wm * 64 + mt * 32 + 4 * h2;
        if (z != 2) {
            const int cb2 = (dd >> 4) * 512 + ((dd >> 3) & 1) * 256 + (dd & 7);
#pragma unroll
            for (int r = 0; r < 16; ++r) {
                const int m = mbase + (r & 3) + 8 * (r >> 2);
                const int bb = m >> 11, q = m & 2047;
                float v = (acc[mt][r] + bn) * scale;
                out[((size_t)((bb * 16 + hh) * 64 + (q >> 5))) * 2048 +
                    cb2 + (q & 31) * 8] = f2bf(v);
            }
        } else {
            const int dblk = dd >> 5, lmv = dd & 31;
#pragma unroll
            for (int g = 0; g < 4; ++g) {
                const int m = mbase + 8 * g;
                const int bb = m >> 11, s = m & 2047;
                const int kvt = s >> 6, kc = (s >> 4) & 3;
                const int h2v = (s >> 3) & 1, j0 = s & 7;
                s4v pq = {f2bf(acc[mt][4 * g + 0] + bn),
                          f2bf(acc[mt][4 * g + 1] + bn),
                          f2bf(acc[mt][4 * g + 2] + bn),
                          f2bf(acc[mt][4 * g + 3] + bn)};
                *(s4v*)(out +
                        ((size_t)(((bb * 16 + hh) * 32 + kvt) * 2 + dblk)) * 2048 +
                        kc * 512 + h2v * 256 + lmv * 8 + j0) = pq;
            }
        }
    }
}

// ---------- output GEMM with fused combine, 128x64 tiles (R20) ------------
// Grid 512 (2 blocks/CU): m = bid&31 (XCD swizzle), n16 = bid>>5 (0..15).
// 512 thr / 8 waves: wm = w&3 (32-row m-strip), wn = w>>2 (32-col n-strip),
// acc[1] per wave. A = (p0+p1)*inv combine (128x32, unchanged); B 4KB/buf
// staged by waves 0-3 (sigma(t) closed under t<256). LDS 24KB.
__global__ __launch_bounds__(512) void gemm_out(
    const short* __restrict__ p0, const short* __restrict__ p1,
    const float* __restrict__ lsum, const short* __restrict__ Bt,
    const float* __restrict__ bias, float* __restrict__ out) {
    constexpr int K = 1024, NIT = 32;
    __shared__ short As[8192];  // 2 x 4096 (A: 128x32 per buf)
    __shared__ short Bs[4096];  // 2 x 2048 (B: 64x32 per buf)
    const int t = threadIdx.x, lane = t & 63, w = t >> 6;  // w 0..7
    const int lm = lane & 31, h2 = lane >> 5;
    const int wm = w & 3, wn = w >> 2;  // wm 0..3, wn 0..1
    const int bid = blockIdx.x;
    const int m0 = (bid & 31) * 128, n0 = (bid >> 5) * 64;

    const int st = t ^ ((t >> 3) & 7);
    const int srow = st >> 2, scol = (st & 3) * 8;
    const int gm = m0 + srow;
    const int b = gm >> 11, q = gm & 2047;
    const short* pa0 = p0 + (size_t)gm * 1024 + scol;
    const short* pa1 = p1 + (size_t)gm * 1024 + scol;
    // B staged by t<256 only (srow<64 there; sigma keeps t<256 closed).
    const short* gb = Bt + (size_t)(n0 + srow) * K + scol;

    float inv[16];
#pragma unroll
    for (int h = 0; h < 16; ++h) {
        float l0 = lsum[((size_t)b * 16 + h) * 2048 + q];
        float l1 = lsum[((size_t)(2 + b) * 16 + h) * 2048 + q];
        inv[h] = 1.f / (l0 + l1);
    }

    const int xorv = (lm >> 1) & 7;
    const int rA0 = wm * 32 + lm, rB0 = wn * 32 + lm;

    accf acc = zero16();

    // prologue: stage iter 0 (B via DMA by waves 0-3, A via combine+ds_write)
    if (t < 256) dma16(gb, &Bs[w * 512]);
    {
        bfr v0 = *(const bfr*)pa0;
        bfr v1 = *(const bfr*)pa1;
        const float iv = inv[0];
        bfr pk;
#pragma unroll
        for (int j = 0; j < 8; ++j)
            pk[j] = f2bf((bf2f(v0[j]) + bf2f(v1[j])) * iv);
        *(bfr*)&As[t * 8] = pk;
    }

#pragma unroll 1
    for (int it = 0; it < NIT; ++it) {
        const int p = it & 1;
        __syncthreads();  // drains buf-p DMA + ds_writes
        bfr v0, v1;
        const bool nxt = (it + 1 < NIT);
        if (nxt) {
            const int ktn = (it + 1) * 32;
            if (t < 256) dma16(gb + ktn, &Bs[(1 - p) * 2048 + w * 512]);
            v0 = *(const bfr*)(pa0 + ktn);
            v1 = *(const bfr*)(pa1 + ktn);
        }
        const short* bA = &As[p * 4096];
        const short* bB = &Bs[p * 2048];
#pragma unroll
        for (int kk8 = 0; kk8 < 4; kk8 += 2) {
            bfr a0 = *(const bfr*)&bA[((rA0 * 4 + h2 + kk8) ^ xorv) * 8];
            bfr b0 = *(const bfr*)&bB[((rB0 * 4 + h2 + kk8) ^ xorv) * 8];
            acc = MFMA32(a0, b0, acc);
        }
        if (nxt) {
            const float iv = inv[(it + 1) >> 1];  // h = kt>>6, iter-uniform
            bfr pk;
#pragma unroll
            for (int j = 0; j < 8; ++j)
                pk[j] = f2bf((bf2f(v0[j]) + bf2f(v1[j])) * iv);
            *(bfr*)&As[(1 - p) * 4096 + t * 8] = pk;
        }
    }

    const int n = n0 + wn * 32 + lm;
    const float bn = bias[n];
    const int mbase = m0 + wm * 32 + 4 * h2;
#pragma unroll
    for (int r = 0; r < 16; ++r) {
        const int m = mbase + (r & 3) + 8 * (r >> 2);
        out[(size_t)m * 1024 + n] = acc[r] + bn;
    }
}

// ---------- flash attention: R11 body, single 1024-block dispatch ---------
__global__ __launch_bounds__(256, 3) void attn(
    const short* __restrict__ Qf, const short* __restrict__ Kf,
    const short* __restrict__ Vt, short* __restrict__ part,
    float* __restrict__ lsum) {
    __shared__ short smem[16384];  // 2 bufs x (K 4KB + V 4KB) = 32 KB
    const int bid = blockIdx.x;
    const int hidx = bid & 31, qs = bid >> 5;
    const int split = qs & 1, qb = qs >> 1;
    const int b = hidx >> 4, h = hidx & 15;
    const int lane = threadIdx.x & 63, wv = threadIdx.x >> 6;
    const int lm = lane & 31, h2 = lane >> 5;
    const bool hb = h2 != 0;
    const int q0 = qb * 128 + wv * 32;

    const short* qbase =
        Qf + ((size_t)(hidx * 64 + (q0 >> 5))) * 2048 + lane * 8;
    bfr qf[4];
#pragma unroll
    for (int kc = 0; kc < 4; ++kc) qf[kc] = *(const bfr*)(qbase + kc * 512);

    const short* khead = Kf + (size_t)hidx * 131072 + split * 65536;
    const short* vhead = Vt + (size_t)hidx * 131072 + split * 65536;
    const short* gsrc =
        ((wv < 2) ? (khead + wv * 2048) : (vhead + (wv - 2) * 2048)) + lane * 8;

#pragma unroll
    for (int i = 0; i < 4; ++i)
        dma16(gsrc + i * 512, &smem[wv * 2048 + i * 512]);

    accf oa0 = zero16(), oa1 = zero16();
    float la0 = 0.f, la1 = 0.f;

#pragma unroll 1
    for (int it = 0; it < 16; ++it) {
        const int p = it & 1;
        __syncthreads();  // buf p DMA drained (vmcnt(0) before s_barrier)
        if (it + 1 < 16) {
            const short* gn = gsrc + (size_t)(it + 1) * 4096;
            short* ln = &smem[(1 - p) * 8192 + wv * 2048];
#pragma unroll
            for (int i = 0; i < 4; ++i) dma16(gn + i * 512, ln + i * 512);
        }
        const short* kb = &smem[p * 8192];
        bfr kf0[4], kf1[4], vf0[4], vf1[4];
#pragma unroll
        for (int kc = 0; kc < 4; ++kc) {
            kf0[kc] = *(const bfr*)&kb[kc * 512 + lane * 8];
            kf1[kc] = *(const bfr*)&kb[2048 + kc * 512 + lane * 8];
            vf0[kc] = *(const bfr*)&kb[4096 + kc * 512 + lane * 8];
            vf1[kc] = *(const bfr*)&kb[6144 + kc * 512 + lane * 8];
        }
        accf s0 = zero16(), s1 = zero16();
#pragma unroll
        for (int kc = 0; kc < 4; ++kc) {
            s0 = MFMA32(kf0[kc], qf[kc], s0);
            s1 = MFMA32(kf1[kc], qf[kc], s1);
        }

#pragma unroll
        for (int i = 0; i < 16; ++i) s0[i] = fexp2(s0[i]);
#pragma unroll
        for (int i = 0; i < 16; ++i) s1[i] = fexp2(s1[i]);
#pragma unroll
        for (int i = 0; i < 16; ++i) {
            if (i & 1) la1 += s0[i] + s1[i];
            else       la0 += s0[i] + s1[i];
        }

        // packed half-swap transpose
        bfr pb[4];
#pragma unroll
        for (int kc = 0; kc < 4; ++kc) {
            const accf& s = (kc < 2) ? s0 : s1;
            const int base = 8 * (kc & 1);
            unsigned Lw0 = __builtin_amdgcn_perm(__float_as_uint(s[base + 1]),
                                                 __float_as_uint(s[base + 0]),
                                                 0x07060302u);
            unsigned Lw1 = __builtin_amdgcn_perm(__float_as_uint(s[base + 3]),
                                                 __float_as_uint(s[base + 2]),
                                                 0x07060302u);
            unsigned Hw0 = __builtin_amdgcn_perm(__float_as_uint(s[base + 5]),
                                                 __float_as_uint(s[base + 4]),
                                                 0x07060302u);
            unsigned Hw1 = __builtin_amdgcn_perm(__float_as_uint(s[base + 7]),
                                                 __float_as_uint(s[base + 6]),
                                                 0x07060302u);
            unsigned c0 = hb ? Lw0 : Hw0;
            unsigned c1 = hb ? Lw1 : Hw1;
            unsigned r0 = (unsigned)__shfl_xor((int)c0, 32);
            unsigned r1 = (unsigned)__shfl_xor((int)c1, 32);
            u4v pw = {hb ? r0 : Lw0, hb ? r1 : Lw1,
                      hb ? Hw0 : r0, hb ? Hw1 : r1};
            pb[kc] = __builtin_bit_cast(bfr, pw);
        }

#pragma unroll
        for (int kc = 0; kc < 4; ++kc) {
            oa0 = MFMA32(vf0[kc], pb[kc], oa0);
            oa1 = MFMA32(vf1[kc], pb[kc], oa1);
        }
    }

    float ls = la0 + la1;
    ls += __shfl_xor(ls, 32);
    if (!hb) lsum[((size_t)(split * 2 + b) * 16 + h) * 2048 + q0 + lm] = ls;

    short* orow = part + (size_t)split * 4194304 +
                  (size_t)(b * 2048 + q0 + lm) * 1024 + h * 64;
#pragma unroll
    for (int dt = 0; dt < 2; ++dt) {
        const accf& oa = dt ? oa1 : oa0;
#pragma unroll
        for (int g = 0; g < 4; ++g) {
            const int d0 = dt * 32 + 4 * h2 + 8 * g;
            s4v p = {f2bf(oa[4 * g + 0]), f2bf(oa[4 * g + 1]),
                     f2bf(oa[4 * g + 2]), f2bf(oa[4 * g + 3])};
            *(s4v*)(orow + d0) = p;
        }
    }
}

}  // namespace

extern "C" void kernel_launch(void* const* d_in, const int* in_sizes, int n_in,
                              void* d_out, int out_size, void* d_ws,
                              size_t ws_size, hipStream_t stream) {
    const float* x   = (const float*)d_in[0];
    const float* ctx = (const float*)d_in[1];
    const float* Wq  = (const float*)d_in[2];
    const float* bq  = (const float*)d_in[3];
    const float* Wk  = (const float*)d_in[4];
    const float* bk  = (const float*)d_in[5];
    const float* Wv  = (const float*)d_in[6];
    const float* bv  = (const float*)d_in[7];
    const float* Wo  = (const float*)d_in[8];
    const float* bo  = (const float*)d_in[9];

    short* xb  = (short*)d_ws;
    short* cb  = xb + (size_t)4096 * 1024;
    short* Wqt = cb + (size_t)4096 * 768;
    short* Wkt = Wqt + (size_t)1024 * 1024;
    short* Wvt = Wkt + (size_t)1024 * 768;
    short* Wot = Wvt + (size_t)1024 * 768;
    short* Qf  = Wot + (size_t)1024 * 1024;  // frag-order, pre-scaled
    short* Kf  = Qf + (size_t)4096 * 1024;   // frag-order
    short* Vt  = Kf + (size_t)4096 * 1024;   // frag-order V^T
    short* p0  = Vt + (size_t)4096 * 1024;   // split partials (unnormalized)
    short* p1  = p0 + (size_t)4096 * 1024;
    float* lsum = (float*)(p1 + (size_t)4096 * 1024);  // [2][2][16][2048]

    prep<<<8192, 256, 0, stream>>>(x, ctx, xb, cb, Wq, Wk, Wv, Wo,
                                   Wqt, Wkt, Wvt, Wot);

    const float qscale = 0.125f * 1.44269504088896f;
    gemm_qkv<<<768, 512, 0, stream>>>(xb, cb, Wqt, Wkt, Wvt,
                                      bq, bk, bv, Qf, Kf, Vt, qscale);

    attn<<<1024, 256, 0, stream>>>(Qf, Kf, Vt, p0, lsum);

    gemm_out<<<512, 512, 0, stream>>>(p0, p1, lsum, Wot, bo, (float*)d_out);
}

// Round 12
// 203.538 us; speedup vs baseline: 1.0451x; 1.0451x over previous
//
#include <hip/hip_runtime.h>
#include <math.h>

// CrossAttention B=2,S=2048,E=1024,H=16,Dh=64,NC=768 — fp32 in/out.
// Ledger: R11 216.4 | R18 215.1 | R19 208.2 (best) | R20 128x64 gemm_out
//   212.7 REGRESSED — root cause: gemm_out's A-path is the fused combine
//   ((p0+p1)*inv + lsum + repack), recomputed per n-tile: 8x at 128x128,
//   16x at 128x64. Occupancy gain swamped by duplicated combine VALU.
// R21: hoist combine out of the GEMM.
//   (1) combine kernel: in-place p0 = (p0+p1)*inv — elementwise, once
//       (~28MB ≈ 5us). In-place safe: disjoint 16B per thread; attn
//       regenerates p0 every iteration before combine.
//   (2) gemm_o: pure GEMM clone of proven R19 gemm_qkv (512thr/8w, 3-deep
//       counted-vmcnt, same sigma staging; p0 layout == xb layout), fp32
//       epilogue from R19 gemm_out. A via dma16 — no combine in loop.
//   attn/qkv/prep byte-identical to R19.

namespace {

typedef short bfr __attribute__((ext_vector_type(8)));   // 8 bf16 = 4 VGPR
typedef short s4v __attribute__((ext_vector_type(4)));
typedef unsigned u4v __attribute__((ext_vector_type(4)));
typedef float accf __attribute__((ext_vector_type(16)));

#define MFMA32(a, b, c) __builtin_amdgcn_mfma_f32_32x32x16_bf16(a, b, c, 0, 0, 0)

__device__ inline short f2bf(float f) {  // RNE
    unsigned u = __float_as_uint(f);
    u += 0x7fffu + ((u >> 16) & 1u);
    return (short)(u >> 16);
}
__device__ inline float bf2f(short s) {
    return __uint_as_float(((unsigned)(unsigned short)s) << 16);
}
__device__ inline float fexp2(float x) { return __builtin_amdgcn_exp2f(x); }
__device__ inline accf zero16() {
    accf z;
#pragma unroll
    for (int i = 0; i < 16; ++i) z[i] = 0.f;
    return z;
}
__device__ inline void dma16(const void* g, void* l) {
    __builtin_amdgcn_global_load_lds(
        (const __attribute__((address_space(1))) void*)g,
        (__attribute__((address_space(3))) void*)l, 16, 0, 0);
}

// ---------- prep: tobf (x,ctx) + all 4 weight transposes, one dispatch ----
__global__ __launch_bounds__(256) void prep(
    const float* __restrict__ x, const float* __restrict__ ctx,
    short* __restrict__ xb, short* __restrict__ cb,
    const float* __restrict__ Wq, const float* __restrict__ Wk,
    const float* __restrict__ Wv, const float* __restrict__ Wo,
    short* __restrict__ Wqt, short* __restrict__ Wkt,
    short* __restrict__ Wvt, short* __restrict__ Wot) {
    __shared__ short t[64][68];
    const int bx = blockIdx.x;
    if (bx < 7168) {  // elementwise fp32->bf16
        int i = bx * 256 + threadIdx.x;
        if (i < 1048576) {
            float4 v = ((const float4*)x)[i];
            s4v p = {f2bf(v.x), f2bf(v.y), f2bf(v.z), f2bf(v.w)};
            ((s4v*)xb)[i] = p;
        } else {
            int j = i - 1048576;
            float4 v = ((const float4*)ctx)[j];
            s4v p = {f2bf(v.x), f2bf(v.y), f2bf(v.z), f2bf(v.w)};
            ((s4v*)cb)[j] = p;
        }
        return;
    }
    const int idx = bx - 7168;  // 0..1023
    const int z = idx >> 8, gy = (idx >> 4) & 15, gx = idx & 15;
    const float* W;
    short* Wt;
    int K;
    switch (z) {
        case 0: W = Wq; Wt = Wqt; K = 1024; break;
        case 1: W = Wk; Wt = Wkt; K = 768; break;
        case 2: W = Wv; Wt = Wvt; K = 768; break;
        default: W = Wo; Wt = Wot; K = 1024; break;
    }
    const int k0 = gy * 64;
    if (k0 >= K) return;
    const int tid = threadIdx.x;
    const int n0 = gx * 64;
    const int kr = tid >> 4, nc = (tid & 15) * 4;
#pragma unroll
    for (int rep = 0; rep < 4; ++rep) {
        int k = kr + rep * 16;
        float4 v = *(const float4*)&W[(size_t)(k0 + k) * 1024 + n0 + nc];
        t[nc + 0][k] = f2bf(v.x);
        t[nc + 1][k] = f2bf(v.y);
        t[nc + 2][k] = f2bf(v.z);
        t[nc + 3][k] = f2bf(v.w);
    }
    __syncthreads();
    const int nr = tid >> 4, kc = (tid & 15) * 4;
#pragma unroll
    for (int rep = 0; rep < 4; ++rep) {
        int n = nr + rep * 16;
        s4v p = {t[n][kc], t[n][kc + 1], t[n][kc + 2], t[n][kc + 3]};
        *(s4v*)&Wt[(size_t)(n0 + n) * K + k0 + kc] = p;
    }
}

// ---------- fused Q/K/V projection GEMM, 512 thr / 8 waves ----------------
// R19: 3-deep counted-vmcnt pipeline. XCD-swizzled 1D grid (768):
// z = bid>>8; local = bid&255; m = local&31, n = local>>5.
__global__ __launch_bounds__(512, 6) void gemm_qkv(
    const short* __restrict__ xb, const short* __restrict__ cb,
    const short* __restrict__ Wqt, const short* __restrict__ Wkt,
    const short* __restrict__ Wvt, const float* __restrict__ bq,
    const float* __restrict__ bk, const float* __restrict__ bv,
    short* __restrict__ Qf, short* __restrict__ Kf, short* __restrict__ Vt,
    float qscale) {
    const int bid = blockIdx.x;
    const int z = bid >> 8;
    const int local = bid & 255;
    const short* A  = (z == 0) ? xb : cb;
    const short* Bt = (z == 0) ? Wqt : ((z == 1) ? Wkt : Wvt);
    const float* bias = (z == 0) ? bq : ((z == 1) ? bk : bv);
    const int K = (z == 0) ? 1024 : 768;
    const int NIT = K / 32;
    const float scale = (z == 0) ? qscale : 1.f;
    short* out = (z == 0) ? Qf : ((z == 1) ? Kf : Vt);

    __shared__ short As[12288];  // 3 x 4096 (triple buffer)
    __shared__ short Bs[12288];
    const int t = threadIdx.x, lane = t & 63, w = t >> 6;  // w 0..7
    const int lm = lane & 31, h2 = lane >> 5;
    const int wm = w & 1, wn = w >> 1;  // wn 0..3
    const int m0 = (local & 31) * 128, n0 = (local >> 5) * 128;

    const int st = t ^ ((t >> 3) & 7);
    const int srow = st >> 2, scol = (st & 3) * 8;
    const short* ga = A + (size_t)(m0 + srow) * K + scol;
    const short* gb = Bt + (size_t)(n0 + srow) * K + scol;

    const int xorv = (lm >> 1) & 7;
    const int rA0 = wm * 64 + lm, rB0 = wn * 32 + lm;

    accf acc[2] = {zero16(), zero16()};

    dma16(ga, &As[w * 512]);
    dma16(gb, &Bs[w * 512]);
    __builtin_amdgcn_sched_barrier(0);
    dma16(ga + 32, &As[4096 + w * 512]);
    dma16(gb + 32, &Bs[4096 + w * 512]);
    __builtin_amdgcn_sched_barrier(0);

    int buf = 0;
#pragma unroll 1
    for (int it = 0; it < NIT; ++it) {
        __builtin_amdgcn_sched_barrier(0);
        asm volatile("s_waitcnt vmcnt(2)" ::: "memory");
        __builtin_amdgcn_s_barrier();
        __builtin_amdgcn_sched_barrier(0);
        {
            const int nx = (it + 2 >= NIT) ? (it + 2 - NIT) : (it + 2);
            const int nb = (buf + 2 >= 3) ? (buf - 1) : (buf + 2);
            dma16(ga + nx * 32, &As[nb * 4096 + w * 512]);
            dma16(gb + nx * 32, &Bs[nb * 4096 + w * 512]);
        }
        const short* bA = &As[buf * 4096];
        const short* bB = &Bs[buf * 4096];
#pragma unroll
        for (int kk8 = 0; kk8 < 4; kk8 += 2) {
            bfr a0 = *(const bfr*)&bA[((rA0 * 4 + h2 + kk8) ^ xorv) * 8];
            bfr a1 = *(const bfr*)&bA[(((rA0 + 32) * 4 + h2 + kk8) ^ xorv) * 8];
            bfr b0 = *(const bfr*)&bB[((rB0 * 4 + h2 + kk8) ^ xorv) * 8];
            acc[0] = MFMA32(a0, b0, acc[0]);
            acc[1] = MFMA32(a1, b0, acc[1]);
        }
        buf = (buf + 1 == 3) ? 0 : buf + 1;
    }
    asm volatile("s_waitcnt vmcnt(0)" ::: "memory");
    __builtin_amdgcn_sched_barrier(0);

    const int n = n0 + wn * 32 + lm;
    const float bn = bias[n];
    const int hh = n >> 6, dd = n & 63;
#pragma unroll
    for (int mt = 0; mt < 2; ++mt) {
        const int mbase = m0 + wm * 64 + mt * 32 + 4 * h2;
        if (z != 2) {
            const int cb2 = (dd >> 4) * 512 + ((dd >> 3) & 1) * 256 + (dd & 7);
#pragma unroll
            for (int r = 0; r < 16; ++r) {
                const int m = mbase + (r & 3) + 8 * (r >> 2);
                const int bb = m >> 11, q = m & 2047;
                float v = (acc[mt][r] + bn) * scale;
                out[((size_t)((bb * 16 + hh) * 64 + (q >> 5))) * 2048 +
                    cb2 + (q & 31) * 8] = f2bf(v);
            }
        } else {
            const int dblk = dd >> 5, lmv = dd & 31;
#pragma unroll
            for (int g = 0; g < 4; ++g) {
                const int m = mbase + 8 * g;
                const int bb = m >> 11, s = m & 2047;
                const int kvt = s >> 6, kc = (s >> 4) & 3;
                const int h2v = (s >> 3) & 1, j0 = s & 7;
                s4v pq = {f2bf(acc[mt][4 * g + 0] + bn),
                          f2bf(acc[mt][4 * g + 1] + bn),
                          f2bf(acc[mt][4 * g + 2] + bn),
                          f2bf(acc[mt][4 * g + 3] + bn)};
                *(s4v*)(out +
                        ((size_t)(((bb * 16 + hh) * 32 + kvt) * 2 + dblk)) * 2048 +
                        kc * 512 + h2v * 256 + lmv * 8 + j0) = pq;
            }
        }
    }
}

// ---------- combine: p0 = (p0 + p1) * inv, in-place, once (R21) -----------
// p0/p1 row-major [4096][1024] bf16, col = h*64+d. 8 shorts/thread;
// an aligned 8-group never crosses an h boundary (8 | 64).
__global__ __launch_bounds__(256) void combine(
    short* __restrict__ p0, const short* __restrict__ p1,
    const float* __restrict__ lsum) {
    const int i = blockIdx.x * 256 + threadIdx.x;  // 0..524287
    const size_t gi = (size_t)i * 8;
    const int row = (int)(gi >> 10), col = (int)(gi & 1023);
    const int h = col >> 6;
    const int b = row >> 11, q = row & 2047;
    const float l0 = lsum[((size_t)b * 16 + h) * 2048 + q];
    const float l1 = lsum[((size_t)(2 + b) * 16 + h) * 2048 + q];
    const float iv = 1.f / (l0 + l1);
    bfr v0 = *(const bfr*)(p0 + gi);
    bfr v1 = *(const bfr*)(p1 + gi);
    bfr pk;
#pragma unroll
    for (int j = 0; j < 8; ++j)
        pk[j] = f2bf((bf2f(v0[j]) + bf2f(v1[j])) * iv);
    *(bfr*)(p0 + gi) = pk;
}

// ---------- output GEMM: pure dma16 GEMM (gemm_qkv clone), fp32 out -------
// A = combined p0 ([4096][1024] bf16, same layout as xb), B = Wot, K=1024.
// Grid 256: m = bid&31 (XCD swizzle), n = bid>>5. 512 thr / 8 waves,
// 3-deep counted-vmcnt ledger identical to gemm_qkv.
__global__ __launch_bounds__(512, 6) void gemm_o(
    const short* __restrict__ Af, const short* __restrict__ Bt,
    const float* __restrict__ bias, float* __restrict__ out) {
    constexpr int K = 1024, NIT = 32;
    __shared__ short As[12288];  // 3 x 4096
    __shared__ short Bs[12288];
    const int t = threadIdx.x, lane = t & 63, w = t >> 6;  // w 0..7
    const int lm = lane & 31, h2 = lane >> 5;
    const int wm = w & 1, wn = w >> 1;  // wn 0..3
    const int bid = blockIdx.x;
    const int m0 = (bid & 31) * 128, n0 = (bid >> 5) * 128;

    const int st = t ^ ((t >> 3) & 7);
    const int srow = st >> 2, scol = (st & 3) * 8;
    const short* ga = Af + (size_t)(m0 + srow) * K + scol;
    const short* gb = Bt + (size_t)(n0 + srow) * K + scol;

    const int xorv = (lm >> 1) & 7;
    const int rA0 = wm * 64 + lm, rB0 = wn * 32 + lm;

    accf acc[2] = {zero16(), zero16()};

    dma16(ga, &As[w * 512]);
    dma16(gb, &Bs[w * 512]);
    __builtin_amdgcn_sched_barrier(0);
    dma16(ga + 32, &As[4096 + w * 512]);
    dma16(gb + 32, &Bs[4096 + w * 512]);
    __builtin_amdgcn_sched_barrier(0);

    int buf = 0;
#pragma unroll 1
    for (int it = 0; it < NIT; ++it) {
        __builtin_amdgcn_sched_barrier(0);
        asm volatile("s_waitcnt vmcnt(2)" ::: "memory");
        __builtin_amdgcn_s_barrier();
        __builtin_amdgcn_sched_barrier(0);
        {
            const int nx = (it + 2 >= NIT) ? (it + 2 - NIT) : (it + 2);
            const int nb = (buf + 2 >= 3) ? (buf - 1) : (buf + 2);
            dma16(ga + nx * 32, &As[nb * 4096 + w * 512]);
            dma16(gb + nx * 32, &Bs[nb * 4096 + w * 512]);
        }
        const short* bA = &As[buf * 4096];
        const short* bB = &Bs[buf * 4096];
#pragma unroll
        for (int kk8 = 0; kk8 < 4; kk8 += 2) {
            bfr a0 = *(const bfr*)&bA[((rA0 * 4 + h2 + kk8) ^ xorv) * 8];
            bfr a1 = *(const bfr*)&bA[(((rA0 + 32) * 4 + h2 + kk8) ^ xorv) * 8];
            bfr b0 = *(const bfr*)&bB[((rB0 * 4 + h2 + kk8) ^ xorv) * 8];
            acc[0] = MFMA32(a0, b0, acc[0]);
            acc[1] = MFMA32(a1, b0, acc[1]);
        }
        buf = (buf + 1 == 3) ? 0 : buf + 1;
    }
    asm volatile("s_waitcnt vmcnt(0)" ::: "memory");
    __builtin_amdgcn_sched_barrier(0);

    const int n = n0 + wn * 32 + lm;
    const float bn = bias[n];
#pragma unroll
    for (int mt = 0; mt < 2; ++mt) {
        const int mbase = m0 + wm * 64 + mt * 32 + 4 * h2;
#pragma unroll
        for (int r = 0; r < 16; ++r) {
            const int m = mbase + (r & 3) + 8 * (r >> 2);
            out[(size_t)m * 1024 + n] = acc[mt][r] + bn;
        }
    }
}

// ---------- flash attention: R11 body, single 1024-block dispatch ---------
__global__ __launch_bounds__(256, 3) void attn(
    const short* __restrict__ Qf, const short* __restrict__ Kf,
    const short* __restrict__ Vt, short* __restrict__ part,
    float* __restrict__ lsum) {
    __shared__ short smem[16384];  // 2 bufs x (K 4KB + V 4KB) = 32 KB
    const int bid = blockIdx.x;
    const int hidx = bid & 31, qs = bid >> 5;
    const int split = qs & 1, qb = qs >> 1;
    const int b = hidx >> 4, h = hidx & 15;
    const int lane = threadIdx.x & 63, wv = threadIdx.x >> 6;
    const int lm = lane & 31, h2 = lane >> 5;
    const bool hb = h2 != 0;
    const int q0 = qb * 128 + wv * 32;

    const short* qbase =
        Qf + ((size_t)(hidx * 64 + (q0 >> 5))) * 2048 + lane * 8;
    bfr qf[4];
#pragma unroll
    for (int kc = 0; kc < 4; ++kc) qf[kc] = *(const bfr*)(qbase + kc * 512);

    const short* khead = Kf + (size_t)hidx * 131072 + split * 65536;
    const short* vhead = Vt + (size_t)hidx * 131072 + split * 65536;
    const short* gsrc =
        ((wv < 2) ? (khead + wv * 2048) : (vhead + (wv - 2) * 2048)) + lane * 8;

#pragma unroll
    for (int i = 0; i < 4; ++i)
        dma16(gsrc + i * 512, &smem[wv * 2048 + i * 512]);

    accf oa0 = zero16(), oa1 = zero16();
    float la0 = 0.f, la1 = 0.f;

#pragma unroll 1
    for (int it = 0; it < 16; ++it) {
        const int p = it & 1;
        __syncthreads();  // buf p DMA drained (vmcnt(0) before s_barrier)
        if (it + 1 < 16) {
            const short* gn = gsrc + (size_t)(it + 1) * 4096;
            short* ln = &smem[(1 - p) * 8192 + wv * 2048];
#pragma unroll
            for (int i = 0; i < 4; ++i) dma16(gn + i * 512, ln + i * 512);
        }
        const short* kb = &smem[p * 8192];
        bfr kf0[4], kf1[4], vf0[4], vf1[4];
#pragma unroll
        for (int kc = 0; kc < 4; ++kc) {
            kf0[kc] = *(const bfr*)&kb[kc * 512 + lane * 8];
            kf1[kc] = *(const bfr*)&kb[2048 + kc * 512 + lane * 8];
            vf0[kc] = *(const bfr*)&kb[4096 + kc * 512 + lane * 8];
            vf1[kc] = *(const bfr*)&kb[6144 + kc * 512 + lane * 8];
        }
        accf s0 = zero16(), s1 = zero16();
#pragma unroll
        for (int kc = 0; kc < 4; ++kc) {
            s0 = MFMA32(kf0[kc], qf[kc], s0);
            s1 = MFMA32(kf1[kc], qf[kc], s1);
        }

#pragma unroll
        for (int i = 0; i < 16; ++i) s0[i] = fexp2(s0[i]);
#pragma unroll
        for (int i = 0; i < 16; ++i) s1[i] = fexp2(s1[i]);
#pragma unroll
        for (int i = 0; i < 16; ++i) {
            if (i & 1) la1 += s0[i] + s1[i];
            else       la0 += s0[i] + s1[i];
        }

        // packed half-swap transpose
        bfr pb[4];
#pragma unroll
        for (int kc = 0; kc < 4; ++kc) {
            const accf& s = (kc < 2) ? s0 : s1;
            const int base = 8 * (kc & 1);
            unsigned Lw0 = __builtin_amdgcn_perm(__float_as_uint(s[base + 1]),
                                                 __float_as_uint(s[base + 0]),
                                                 0x07060302u);
            unsigned Lw1 = __builtin_amdgcn_perm(__float_as_uint(s[base + 3]),
                                                 __float_as_uint(s[base + 2]),
                                                 0x07060302u);
            unsigned Hw0 = __builtin_amdgcn_perm(__float_as_uint(s[base + 5]),
                                                 __float_as_uint(s[base + 4]),
                                                 0x07060302u);
            unsigned Hw1 = __builtin_amdgcn_perm(__float_as_uint(s[base + 7]),
                                                 __float_as_uint(s[base + 6]),
                                                 0x07060302u);
            unsigned c0 = hb ? Lw0 : Hw0;
            unsigned c1 = hb ? Lw1 : Hw1;
            unsigned r0 = (unsigned)__shfl_xor((int)c0, 32);
            unsigned r1 = (unsigned)__shfl_xor((int)c1, 32);
            u4v pw = {hb ? r0 : Lw0, hb ? r1 : Lw1,
                      hb ? Hw0 : r0, hb ? Hw1 : r1};
            pb[kc] = __builtin_bit_cast(bfr, pw);
        }

#pragma unroll
        for (int kc = 0; kc < 4; ++kc) {
            oa0 = MFMA32(vf0[kc], pb[kc], oa0);
            oa1 = MFMA32(vf1[kc], pb[kc], oa1);
        }
    }

    float ls = la0 + la1;
    ls += __shfl_xor(ls, 32);
    if (!hb) lsum[((size_t)(split * 2 + b) * 16 + h) * 2048 + q0 + lm] = ls;

    short* orow = part + (size_t)split * 4194304 +
                  (size_t)(b * 2048 + q0 + lm) * 1024 + h * 64;
#pragma unroll
    for (int dt = 0; dt < 2; ++dt) {
        const accf& oa = dt ? oa1 : oa0;
#pragma unroll
        for (int g = 0; g < 4; ++g) {
            const int d0 = dt * 32 + 4 * h2 + 8 * g;
            s4v p = {f2bf(oa[4 * g + 0]), f2bf(oa[4 * g + 1]),
                     f2bf(oa[4 * g + 2]), f2bf(oa[4 * g + 3])};
            *(s4v*)(orow + d0) = p;
        }
    }
}

}  // namespace

extern "C" void kernel_launch(void* const* d_in, const int* in_sizes, int n_in,
                              void* d_out, int out_size, void* d_ws,
                              size_t ws_size, hipStream_t stream) {
    const float* x   = (const float*)d_in[0];
    const float* ctx = (const float*)d_in[1];
    const float* Wq  = (const float*)d_in[2];
    const float* bq  = (const float*)d_in[3];
    const float* Wk  = (const float*)d_in[4];
    const float* bk  = (const float*)d_in[5];
    const float* Wv  = (const float*)d_in[6];
    const float* bv  = (const float*)d_in[7];
    const float* Wo  = (const float*)d_in[8];
    const float* bo  = (const float*)d_in[9];

    short* xb  = (short*)d_ws;
    short* cb  = xb + (size_t)4096 * 1024;
    short* Wqt = cb + (size_t)4096 * 768;
    short* Wkt = Wqt + (size_t)1024 * 1024;
    short* Wvt = Wkt + (size_t)1024 * 768;
    short* Wot = Wvt + (size_t)1024 * 768;
    short* Qf  = Wot + (size_t)1024 * 1024;  // frag-order, pre-scaled
    short* Kf  = Qf + (size_t)4096 * 1024;   // frag-order
    short* Vt  = Kf + (size_t)4096 * 1024;   // frag-order V^T
    short* p0  = Vt + (size_t)4096 * 1024;   // split partials (unnormalized)
    short* p1  = p0 + (size_t)4096 * 1024;
    float* lsum = (float*)(p1 + (size_t)4096 * 1024);  // [2][2][16][2048]

    prep<<<8192, 256, 0, stream>>>(x, ctx, xb, cb, Wq, Wk, Wv, Wo,
                                   Wqt, Wkt, Wvt, Wot);

    const float qscale = 0.125f * 1.44269504088896f;
    gemm_qkv<<<768, 512, 0, stream>>>(xb, cb, Wqt, Wkt, Wvt,
                                      bq, bk, bv, Qf, Kf, Vt, qscale);

    attn<<<1024, 256, 0, stream>>>(Qf, Kf, Vt, p0, lsum);

    combine<<<2048, 256, 0, stream>>>(p0, p1, lsum);

    gemm_o<<<256, 512, 0, stream>>>(p0, Wot, bo, (float*)d_out);
}

// Round 13
// 196.792 us; speedup vs baseline: 1.0809x; 1.0343x over previous
//
#include <hip/hip_runtime.h>
#include <math.h>

// CrossAttention B=2,S=2048,E=1024,H=16,Dh=64,NC=768 — fp32 in/out.
// Ledger: R11 216.4 | R18 215.1 | R19 208.2 | R20 212.7 (combine-dup) |
//   R21 203.5 (combine hoisted + pure gemm_o) — best.
// R22: (1) attn KV-split removed (32 iters/block, grid 512 = uniform 2/CU):
//   full softmax denom is in-register -> normalize in epilogue (iv=1/ls,
//   every lane holds its q-row's ls after shfl_xor(32)), write final bf16.
//   Kills combine dispatch (-5us), p1 writes (-8.4MB), all lsum traffic.
//   (2) gemm_o retile 128x128 -> 128x64: grid 512 (2 blocks/CU vs 1) —
//   R20's validated decomposition (wm=w&3/wn=w>>2/acc[1]; sigma closed
//   under t<256) + R19's 3-deep counted-vmcnt ledger. B staged by waves
//   0-3; wave-uniform vmcnt(2)/vmcnt(1) per staging role (if-converted
//   fallback vmcnt(1)-for-all is conservative-safe).
//   prep/gemm_qkv byte-identical to R21.

namespace {

typedef short bfr __attribute__((ext_vector_type(8)));   // 8 bf16 = 4 VGPR
typedef short s4v __attribute__((ext_vector_type(4)));
typedef unsigned u4v __attribute__((ext_vector_type(4)));
typedef float accf __attribute__((ext_vector_type(16)));

#define MFMA32(a, b, c) __builtin_amdgcn_mfma_f32_32x32x16_bf16(a, b, c, 0, 0, 0)

__device__ inline short f2bf(float f) {  // RNE
    unsigned u = __float_as_uint(f);
    u += 0x7fffu + ((u >> 16) & 1u);
    return (short)(u >> 16);
}
__device__ inline float bf2f(short s) {
    return __uint_as_float(((unsigned)(unsigned short)s) << 16);
}
__device__ inline float fexp2(float x) { return __builtin_amdgcn_exp2f(x); }
__device__ inline accf zero16() {
    accf z;
#pragma unroll
    for (int i = 0; i < 16; ++i) z[i] = 0.f;
    return z;
}
__device__ inline void dma16(const void* g, void* l) {
    __builtin_amdgcn_global_load_lds(
        (const __attribute__((address_space(1))) void*)g,
        (__attribute__((address_space(3))) void*)l, 16, 0, 0);
}

// ---------- prep: tobf (x,ctx) + all 4 weight transposes, one dispatch ----
__global__ __launch_bounds__(256) void prep(
    const float* __restrict__ x, const float* __restrict__ ctx,
    short* __restrict__ xb, short* __restrict__ cb,
    const float* __restrict__ Wq, const float* __restrict__ Wk,
    const float* __restrict__ Wv, const float* __restrict__ Wo,
    short* __restrict__ Wqt, short* __restrict__ Wkt,
    short* __restrict__ Wvt, short* __restrict__ Wot) {
    __shared__ short t[64][68];
    const int bx = blockIdx.x;
    if (bx < 7168) {  // elementwise fp32->bf16
        int i = bx * 256 + threadIdx.x;
        if (i < 1048576) {
            float4 v = ((const float4*)x)[i];
            s4v p = {f2bf(v.x), f2bf(v.y), f2bf(v.z), f2bf(v.w)};
            ((s4v*)xb)[i] = p;
        } else {
            int j = i - 1048576;
            float4 v = ((const float4*)ctx)[j];
            s4v p = {f2bf(v.x), f2bf(v.y), f2bf(v.z), f2bf(v.w)};
            ((s4v*)cb)[j] = p;
        }
        return;
    }
    const int idx = bx - 7168;  // 0..1023
    const int z = idx >> 8, gy = (idx >> 4) & 15, gx = idx & 15;
    const float* W;
    short* Wt;
    int K;
    switch (z) {
        case 0: W = Wq; Wt = Wqt; K = 1024; break;
        case 1: W = Wk; Wt = Wkt; K = 768; break;
        case 2: W = Wv; Wt = Wvt; K = 768; break;
        default: W = Wo; Wt = Wot; K = 1024; break;
    }
    const int k0 = gy * 64;
    if (k0 >= K) return;
    const int tid = threadIdx.x;
    const int n0 = gx * 64;
    const int kr = tid >> 4, nc = (tid & 15) * 4;
#pragma unroll
    for (int rep = 0; rep < 4; ++rep) {
        int k = kr + rep * 16;
        float4 v = *(const float4*)&W[(size_t)(k0 + k) * 1024 + n0 + nc];
        t[nc + 0][k] = f2bf(v.x);
        t[nc + 1][k] = f2bf(v.y);
        t[nc + 2][k] = f2bf(v.z);
        t[nc + 3][k] = f2bf(v.w);
    }
    __syncthreads();
    const int nr = tid >> 4, kc = (tid & 15) * 4;
#pragma unroll
    for (int rep = 0; rep < 4; ++rep) {
        int n = nr + rep * 16;
        s4v p = {t[n][kc], t[n][kc + 1], t[n][kc + 2], t[n][kc + 3]};
        *(s4v*)&Wt[(size_t)(n0 + n) * K + k0 + kc] = p;
    }
}

// ---------- fused Q/K/V projection GEMM, 512 thr / 8 waves ----------------
// R19: 3-deep counted-vmcnt pipeline. XCD-swizzled 1D grid (768):
// z = bid>>8; local = bid&255; m = local&31, n = local>>5.
__global__ __launch_bounds__(512, 6) void gemm_qkv(
    const short* __restrict__ xb, const short* __restrict__ cb,
    const short* __restrict__ Wqt, const short* __restrict__ Wkt,
    const short* __restrict__ Wvt, const float* __restrict__ bq,
    const float* __restrict__ bk, const float* __restrict__ bv,
    short* __restrict__ Qf, short* __restrict__ Kf, short* __restrict__ Vt,
    float qscale) {
    const int bid = blockIdx.x;
    const int z = bid >> 8;
    const int local = bid & 255;
    const short* A  = (z == 0) ? xb : cb;
    const short* Bt = (z == 0) ? Wqt : ((z == 1) ? Wkt : Wvt);
    const float* bias = (z == 0) ? bq : ((z == 1) ? bk : bv);
    const int K = (z == 0) ? 1024 : 768;
    const int NIT = K / 32;
    const float scale = (z == 0) ? qscale : 1.f;
    short* out = (z == 0) ? Qf : ((z == 1) ? Kf : Vt);

    __shared__ short As[12288];  // 3 x 4096 (triple buffer)
    __shared__ short Bs[12288];
    const int t = threadIdx.x, lane = t & 63, w = t >> 6;  // w 0..7
    const int lm = lane & 31, h2 = lane >> 5;
    const int wm = w & 1, wn = w >> 1;  // wn 0..3
    const int m0 = (local & 31) * 128, n0 = (local >> 5) * 128;

    const int st = t ^ ((t >> 3) & 7);
    const int srow = st >> 2, scol = (st & 3) * 8;
    const short* ga = A + (size_t)(m0 + srow) * K + scol;
    const short* gb = Bt + (size_t)(n0 + srow) * K + scol;

    const int xorv = (lm >> 1) & 7;
    const int rA0 = wm * 64 + lm, rB0 = wn * 32 + lm;

    accf acc[2] = {zero16(), zero16()};

    dma16(ga, &As[w * 512]);
    dma16(gb, &Bs[w * 512]);
    __builtin_amdgcn_sched_barrier(0);
    dma16(ga + 32, &As[4096 + w * 512]);
    dma16(gb + 32, &Bs[4096 + w * 512]);
    __builtin_amdgcn_sched_barrier(0);

    int buf = 0;
#pragma unroll 1
    for (int it = 0; it < NIT; ++it) {
        __builtin_amdgcn_sched_barrier(0);
        asm volatile("s_waitcnt vmcnt(2)" ::: "memory");
        __builtin_amdgcn_s_barrier();
        __builtin_amdgcn_sched_barrier(0);
        {
            const int nx = (it + 2 >= NIT) ? (it + 2 - NIT) : (it + 2);
            const int nb = (buf + 2 >= 3) ? (buf - 1) : (buf + 2);
            dma16(ga + nx * 32, &As[nb * 4096 + w * 512]);
            dma16(gb + nx * 32, &Bs[nb * 4096 + w * 512]);
        }
        const short* bA = &As[buf * 4096];
        const short* bB = &Bs[buf * 4096];
#pragma unroll
        for (int kk8 = 0; kk8 < 4; kk8 += 2) {
            bfr a0 = *(const bfr*)&bA[((rA0 * 4 + h2 + kk8) ^ xorv) * 8];
            bfr a1 = *(const bfr*)&bA[(((rA0 + 32) * 4 + h2 + kk8) ^ xorv) * 8];
            bfr b0 = *(const bfr*)&bB[((rB0 * 4 + h2 + kk8) ^ xorv) * 8];
            acc[0] = MFMA32(a0, b0, acc[0]);
            acc[1] = MFMA32(a1, b0, acc[1]);
        }
        buf = (buf + 1 == 3) ? 0 : buf + 1;
    }
    asm volatile("s_waitcnt vmcnt(0)" ::: "memory");
    __builtin_amdgcn_sched_barrier(0);

    const int n = n0 + wn * 32 + lm;
    const float bn = bias[n];
    const int hh = n >> 6, dd = n & 63;
#pragma unroll
    for (int mt = 0; mt < 2; ++mt) {
        const int mbase = m0 + wm * 64 + mt * 32 + 4 * h2;
        if (z != 2) {
            const int cb2 = (dd >> 4) * 512 + ((dd >> 3) & 1) * 256 + (dd & 7);
#pragma unroll
            for (int r = 0; r < 16; ++r) {
                const int m = mbase + (r & 3) + 8 * (r >> 2);
                const int bb = m >> 11, q = m & 2047;
                float v = (acc[mt][r] + bn) * scale;
                out[((size_t)((bb * 16 + hh) * 64 + (q >> 5))) * 2048 +
                    cb2 + (q & 31) * 8] = f2bf(v);
            }
        } else {
            const int dblk = dd >> 5, lmv = dd & 31;
#pragma unroll
            for (int g = 0; g < 4; ++g) {
                const int m = mbase + 8 * g;
                const int bb = m >> 11, s = m & 2047;
                const int kvt = s >> 6, kc = (s >> 4) & 3;
                const int h2v = (s >> 3) & 1, j0 = s & 7;
                s4v pq = {f2bf(acc[mt][4 * g + 0] + bn),
                          f2bf(acc[mt][4 * g + 1] + bn),
                          f2bf(acc[mt][4 * g + 2] + bn),
                          f2bf(acc[mt][4 * g + 3] + bn)};
                *(s4v*)(out +
                        ((size_t)(((bb * 16 + hh) * 32 + kvt) * 2 + dblk)) * 2048 +
                        kc * 512 + h2v * 256 + lmv * 8 + j0) = pq;
            }
        }
    }
}

// ---------- output GEMM: 128x64 tiles, 3-deep counted-vmcnt (R22) ---------
// Grid 512 (2 blocks/CU): m = bid&31 (XCD swizzle), n = bid>>5 (0..15).
// 8 waves: wm = w&3 (32-row strip), wn = w>>2 (32-col strip), acc[1]/wave.
// A (128x32/buf, 8KB) staged by all 512 thr; B (64x32/buf, 4KB) by waves
// 0-3 (sigma closed under t<256). Wave-uniform vmcnt: 2 for A+B waves,
// 1 for A-only waves (if-converted vmcnt(1)-for-all is conservative-safe).
__global__ __launch_bounds__(512, 6) void gemm_o(
    const short* __restrict__ Af, const short* __restrict__ Bt,
    const float* __restrict__ bias, float* __restrict__ out) {
    constexpr int K = 1024, NIT = 32;
    __shared__ short As[12288];  // 3 x 4096
    __shared__ short Bs[6144];   // 3 x 2048
    const int t = threadIdx.x, lane = t & 63, w = t >> 6;  // w 0..7
    const int lm = lane & 31, h2 = lane >> 5;
    const int wm = w & 3, wn = w >> 2;  // wm 0..3, wn 0..1
    const int bid = blockIdx.x;
    const int m0 = (bid & 31) * 128, n0 = (bid >> 5) * 64;

    const int st = t ^ ((t >> 3) & 7);
    const int srow = st >> 2, scol = (st & 3) * 8;
    const short* ga = Af + (size_t)(m0 + srow) * K + scol;
    const short* gb = Bt + (size_t)(n0 + srow) * K + scol;  // used t<256
    const bool bw = (w < 4);  // wave-uniform: B-staging waves

    const int xorv = (lm >> 1) & 7;
    const int rA0 = wm * 32 + lm, rB0 = wn * 32 + lm;

    accf acc = zero16();

    // prologue: batches 0,1
    dma16(ga, &As[w * 512]);
    if (bw) dma16(gb, &Bs[w * 512]);
    __builtin_amdgcn_sched_barrier(0);
    dma16(ga + 32, &As[4096 + w * 512]);
    if (bw) dma16(gb + 32, &Bs[2048 + w * 512]);
    __builtin_amdgcn_sched_barrier(0);

    int buf = 0;
#pragma unroll 1
    for (int it = 0; it < NIT; ++it) {
        __builtin_amdgcn_sched_barrier(0);
        if (bw) {
            asm volatile("s_waitcnt vmcnt(2)" ::: "memory");
        } else {
            asm volatile("s_waitcnt vmcnt(1)" ::: "memory");
        }
        __builtin_amdgcn_s_barrier();
        __builtin_amdgcn_sched_barrier(0);
        {
            const int nx = (it + 2 >= NIT) ? (it + 2 - NIT) : (it + 2);
            const int nb = (buf + 2 >= 3) ? (buf - 1) : (buf + 2);
            dma16(ga + nx * 32, &As[nb * 4096 + w * 512]);
            if (bw) dma16(gb + nx * 32, &Bs[nb * 2048 + w * 512]);
        }
        const short* bA = &As[buf * 4096];
        const short* bB = &Bs[buf * 2048];
#pragma unroll
        for (int kk8 = 0; kk8 < 4; kk8 += 2) {
            bfr a0 = *(const bfr*)&bA[((rA0 * 4 + h2 + kk8) ^ xorv) * 8];
            bfr b0 = *(const bfr*)&bB[((rB0 * 4 + h2 + kk8) ^ xorv) * 8];
            acc = MFMA32(a0, b0, acc);
        }
        buf = (buf + 1 == 3) ? 0 : buf + 1;
    }
    asm volatile("s_waitcnt vmcnt(0)" ::: "memory");
    __builtin_amdgcn_sched_barrier(0);

    const int n = n0 + wn * 32 + lm;
    const float bn = bias[n];
    const int mbase = m0 + wm * 32 + 4 * h2;
#pragma unroll
    for (int r = 0; r < 16; ++r) {
        const int m = mbase + (r & 3) + 8 * (r >> 2);
        out[(size_t)m * 1024 + n] = acc[r] + bn;
    }
}

// ---------- flash attention: full-KV blocks, in-register normalize (R22) --
// Grid 512: hidx = bid&31, qb = bid>>5 (0..15). 32 iters x 64 KV rows.
// Epilogue: iv = 1/ls (ls complete after shfl_xor(32)), write final bf16.
__global__ __launch_bounds__(256, 3) void attn(
    const short* __restrict__ Qf, const short* __restrict__ Kf,
    const short* __restrict__ Vt, short* __restrict__ part) {
    __shared__ short smem[16384];  // 2 bufs x (K 4KB + V 4KB) = 32 KB
    const int bid = blockIdx.x;
    const int hidx = bid & 31, qb = bid >> 5;
    const int b = hidx >> 4, h = hidx & 15;
    const int lane = threadIdx.x & 63, wv = threadIdx.x >> 6;
    const int lm = lane & 31, h2 = lane >> 5;
    const bool hb = h2 != 0;
    const int q0 = qb * 128 + wv * 32;

    const short* qbase =
        Qf + ((size_t)(hidx * 64 + (q0 >> 5))) * 2048 + lane * 8;
    bfr qf[4];
#pragma unroll
    for (int kc = 0; kc < 4; ++kc) qf[kc] = *(const bfr*)(qbase + kc * 512);

    const short* khead = Kf + (size_t)hidx * 131072;
    const short* vhead = Vt + (size_t)hidx * 131072;
    const short* gsrc =
        ((wv < 2) ? (khead + wv * 2048) : (vhead + (wv - 2) * 2048)) + lane * 8;

#pragma unroll
    for (int i = 0; i < 4; ++i)
        dma16(gsrc + i * 512, &smem[wv * 2048 + i * 512]);

    accf oa0 = zero16(), oa1 = zero16();
    float la0 = 0.f, la1 = 0.f;

#pragma unroll 1
    for (int it = 0; it < 32; ++it) {
        const int p = it & 1;
        __syncthreads();  // buf p DMA drained (vmcnt(0) before s_barrier)
        if (it + 1 < 32) {
            const short* gn = gsrc + (size_t)(it + 1) * 4096;
            short* ln = &smem[(1 - p) * 8192 + wv * 2048];
#pragma unroll
            for (int i = 0; i < 4; ++i) dma16(gn + i * 512, ln + i * 512);
        }
        const short* kb = &smem[p * 8192];
        bfr kf0[4], kf1[4], vf0[4], vf1[4];
#pragma unroll
        for (int kc = 0; kc < 4; ++kc) {
            kf0[kc] = *(const bfr*)&kb[kc * 512 + lane * 8];
            kf1[kc] = *(const bfr*)&kb[2048 + kc * 512 + lane * 8];
            vf0[kc] = *(const bfr*)&kb[4096 + kc * 512 + lane * 8];
            vf1[kc] = *(const bfr*)&kb[6144 + kc * 512 + lane * 8];
        }
        accf s0 = zero16(), s1 = zero16();
#pragma unroll
        for (int kc = 0; kc < 4; ++kc) {
            s0 = MFMA32(kf0[kc], qf[kc], s0);
            s1 = MFMA32(kf1[kc], qf[kc], s1);
        }

#pragma unroll
        for (int i = 0; i < 16; ++i) s0[i] = fexp2(s0[i]);
#pragma unroll
        for (int i = 0; i < 16; ++i) s1[i] = fexp2(s1[i]);
#pragma unroll
        for (int i = 0; i < 16; ++i) {
            if (i & 1) la1 += s0[i] + s1[i];
            else       la0 += s0[i] + s1[i];
        }

        // packed half-swap transpose
        bfr pb[4];
#pragma unroll
        for (int kc = 0; kc < 4; ++kc) {
            const accf& s = (kc < 2) ? s0 : s1;
            const int base = 8 * (kc & 1);
            unsigned Lw0 = __builtin_amdgcn_perm(__float_as_uint(s[base + 1]),
                                                 __float_as_uint(s[base + 0]),
                                                 0x07060302u);
            unsigned Lw1 = __builtin_amdgcn_perm(__float_as_uint(s[base + 3]),
                                                 __float_as_uint(s[base + 2]),
                                                 0x07060302u);
            unsigned Hw0 = __builtin_amdgcn_perm(__float_as_uint(s[base + 5]),
                                                 __float_as_uint(s[base + 4]),
                                                 0x07060302u);
            unsigned Hw1 = __builtin_amdgcn_perm(__float_as_uint(s[base + 7]),
                                                 __float_as_uint(s[base + 6]),
                                                 0x07060302u);
            unsigned c0 = hb ? Lw0 : Hw0;
            unsigned c1 = hb ? Lw1 : Hw1;
            unsigned r0 = (unsigned)__shfl_xor((int)c0, 32);
            unsigned r1 = (unsigned)__shfl_xor((int)c1, 32);
            u4v pw = {hb ? r0 : Lw0, hb ? r1 : Lw1,
                      hb ? Hw0 : r0, hb ? Hw1 : r1};
            pb[kc] = __builtin_bit_cast(bfr, pw);
        }

#pragma unroll
        for (int kc = 0; kc < 4; ++kc) {
            oa0 = MFMA32(vf0[kc], pb[kc], oa0);
            oa1 = MFMA32(vf1[kc], pb[kc], oa1);
        }
    }

    float ls = la0 + la1;
    ls += __shfl_xor(ls, 32);
    const float iv = 1.f / ls;

    short* orow = part + (size_t)(b * 2048 + q0 + lm) * 1024 + h * 64;
#pragma unroll
    for (int dt = 0; dt < 2; ++dt) {
        const accf& oa = dt ? oa1 : oa0;
#pragma unroll
        for (int g = 0; g < 4; ++g) {
            const int d0 = dt * 32 + 4 * h2 + 8 * g;
            s4v p = {f2bf(oa[4 * g + 0] * iv), f2bf(oa[4 * g + 1] * iv),
                     f2bf(oa[4 * g + 2] * iv), f2bf(oa[4 * g + 3] * iv)};
            *(s4v*)(orow + d0) = p;
        }
    }
}

}  // namespace

extern "C" void kernel_launch(void* const* d_in, const int* in_sizes, int n_in,
                              void* d_out, int out_size, void* d_ws,
                              size_t ws_size, hipStream_t stream) {
    const float* x   = (const float*)d_in[0];
    const float* ctx = (const float*)d_in[1];
    const float* Wq  = (const float*)d_in[2];
    const float* bq  = (const float*)d_in[3];
    const float* Wk  = (const float*)d_in[4];
    const float* bk  = (const float*)d_in[5];
    const float* Wv  = (const float*)d_in[6];
    const float* bv  = (const float*)d_in[7];
    const float* Wo  = (const float*)d_in[8];
    const float* bo  = (const float*)d_in[9];

    short* xb  = (short*)d_ws;
    short* cb  = xb + (size_t)4096 * 1024;
    short* Wqt = cb + (size_t)4096 * 768;
    short* Wkt = Wqt + (size_t)1024 * 1024;
    short* Wvt = Wkt + (size_t)1024 * 768;
    short* Wot = Wvt + (size_t)1024 * 768;
    short* Qf  = Wot + (size_t)1024 * 1024;  // frag-order, pre-scaled
    short* Kf  = Qf + (size_t)4096 * 1024;   // frag-order
    short* Vt  = Kf + (size_t)4096 * 1024;   // frag-order V^T
    short* p0  = Vt + (size_t)4096 * 1024;   // final normalized attn out

    prep<<<8192, 256, 0, stream>>>(x, ctx, xb, cb, Wq, Wk, Wv, Wo,
                                   Wqt, Wkt, Wvt, Wot);

    const float qscale = 0.125f * 1.44269504088896f;
    gemm_qkv<<<768, 512, 0, stream>>>(xb, cb, Wqt, Wkt, Wvt,
                                      bq, bk, bv, Qf, Kf, Vt, qscale);

    attn<<<512, 256, 0, stream>>>(Qf, Kf, Vt, p0);

    gemm_o<<<512, 512, 0, stream>>>(p0, Wot, bo, (float*)d_out);
}